// Round 1
// baseline (588.989 us; speedup 1.0000x reference)
//
#include <hip/hip_runtime.h>
#include <hip/hip_bf16.h>
#include <stdint.h>

#define DEV __device__ __forceinline__

typedef float f32x4 __attribute__((ext_vector_type(4)));
typedef __bf16 bf16x8 __attribute__((ext_vector_type(8)));

DEV float bflo(uint32_t u){ return __uint_as_float(u << 16); }
DEV float bfhi(uint32_t u){ return __uint_as_float(u & 0xffff0000u); }
DEV uint32_t f2bf2(float x, float y){
  union { __hip_bfloat16 b[2]; uint32_t u; } cv;
  cv.b[0] = __float2bfloat16(x); cv.b[1] = __float2bfloat16(y);
  return cv.u;
}

// relative-coordinate values (matches reference _rel_index, f32 semantics)
DEV float relc(int j){
  if (j < 17) return (float)(j - 8);
  if (j < 22) return (float)(j - 19) * 3.4f;   // (i-2) * 17/5
  return 0.0f;
}
DEV int band_of(int t){ return t < 17 ? 0 : (t < 22 ? 1 : 2); }

// avgpool1d index map over the concatenated 23-axis -> 13 pooled slots.
// val = 0.5*(x[a]+x[b]); singletons use a==b.
template<int MODE> DEV void pool_map(int u, int& a, int& b){
  if (MODE == 0){ a = u; b = u; return; }
  if (u == 0){ a = 0; b = 0; }
  else if (u < 9){ a = 2*u - 1; b = 2*u; }
  else if (u == 9){ a = 17; b = 17; }
  else if (u < 12){ a = 2*u - 2; b = 2*u - 1; }
  else { a = 22; b = 22; }
}

DEV float interp_tab(const float* tab, int H, int h, int t, int u){
  float idx = relc(t) - relc(u) + 16.0f;
  float fl = floorf(idx);
  float ce = ceilf(idx);
  int fi = (int)fminf(fmaxf(fl, 0.f), 1088.f);
  int ci = (int)fminf(fmaxf(ce, 0.f), 1088.f);
  float w = idx - fl;
  return (1.0f - w) * tab[fi*H + h] + w * tab[ci*H + h];
}

// ---------------- prep: pos-embed tables + weight bf16 conversion ----------------
__global__ __launch_bounds__(256) void prep_kernel(
    const float* __restrict__ htab, const float* __restrict__ habs,
    const float* __restrict__ ltab, const float* __restrict__ labs,
    const float* __restrict__ hw, const float* __restrict__ lw,
    float* __restrict__ pe_h, float* __restrict__ pe_l,
    __hip_bfloat16* __restrict__ whb, __hip_bfloat16* __restrict__ wlb)
{
  int i = blockIdx.x * 256 + threadIdx.x;
  if (i < 1048576){ whb[i] = __float2bfloat16(hw[i]); return; }
  if (i < 2097152){ int k = i - 1048576; wlb[k] = __float2bfloat16(lw[k]); return; }
  int j = i - 2097152;
  if (j < 529){
    int t = j / 23, u = j % 23;
    pe_h[j] = interp_tab(htab, 1, 0, t, u) + habs[band_of(t)];
    return;
  }
  j -= 529;
  if (j < 897){
    int h = j / 299, r = j % 299, t = r / 13, u = r % 13;
    int a, b; pool_map<1>(u, a, b);
    float v = 0.5f * (interp_tab(ltab, 3, h, t, a) + interp_tab(ltab, 3, h, t, b));
    pe_l[j] = v + labs[band_of(t)*3 + h];  // pe_l[(h*23+t)*13+u]
  }
}

// ---------------- attention: one block per (b,h,d) group ----------------
// MODE 0 = hifi (H=1, U=23, no pooling), MODE 1 = lofi (H=3, U=13, pooled K/V)
template<int MODE>
__global__ __launch_bounds__(256) void attn_kernel(
    const float* __restrict__ x0, const float* __restrict__ x1, const float* __restrict__ x2,
    const float* __restrict__ pe, __hip_bfloat16* __restrict__ O)
{
  constexpr int U = (MODE == 0) ? 23 : 13;
  constexpr int H = (MODE == 0) ? 1 : 3;
  __shared__ __align__(16) __hip_bfloat16 lds_k[U][1024];
  __shared__ __align__(16) float lds_q[1024];
  __shared__ float lds_A[23][U];
  __shared__ float lds_ikn[U];

  const int g = blockIdx.x;
  int b, h, d;
  if (MODE == 0){ b = g >> 6; h = 0; d = g & 63; }
  else { b = g / 192; int rem = g % 192; h = rem >> 6; d = rem & 63; }
  const int tid  = threadIdx.x;
  const int lane = tid & 63, wid = tid >> 6;

  // sel: 0=q 1=k 2=v; t in [0,23) over the concatenated band axis
  auto rowptr = [&](int sel, int t) -> const float* {
    if (t < 17) return x0 + (size_t)((((sel*4 + b)*H + h)*64 + d)*17 + t) * 1024;
    if (t < 22) return x1 + (size_t)((((sel*4 + b)*H + h)*64 + d)*5 + (t - 17)) * 1024;
    return x2 + (size_t)(((sel*4 + b)*H + h)*64 + d) * 1024;
  };

  // Phase 0: stage (pooled) K rows into LDS as bf16
  #pragma unroll
  for (int u = 0; u < U; ++u){
    int au, bu; pool_map<MODE>(u, au, bu);
    const float4* pa = (const float4*)rowptr(1, au);
    const float4* pb = (const float4*)rowptr(1, bu);
    float4 va = pa[tid], vb = pb[tid];
    uint2 pk;
    pk.x = f2bf2(0.5f*(va.x+vb.x), 0.5f*(va.y+vb.y));
    pk.y = f2bf2(0.5f*(va.z+vb.z), 0.5f*(va.w+vb.w));
    ((uint2*)(&lds_k[u][0]))[tid] = pk;
  }
  __syncthreads();

  // Phase 1: inverse norms of (pooled) K rows
  const uint32_t* lk32 = (const uint32_t*)(&lds_k[0][0]);
  for (int u = wid; u < U; u += 4){
    float s = 0.f;
    #pragma unroll
    for (int j2 = 0; j2 < 8; ++j2){
      uint32_t kk = lk32[u*512 + lane + 64*j2];
      float a0 = bflo(kk), a1 = bfhi(kk);
      s += a0*a0 + a1*a1;
    }
    #pragma unroll
    for (int off = 32; off; off >>= 1) s += __shfl_xor(s, off);
    if (lane == 0) lds_ikn[u] = 1.0f / fmaxf(sqrtf(s), 1e-12f);
  }
  __syncthreads();

  // Phase 2: scores A[t][u] = cos(q_t, k_u) + pe
  for (int t = 0; t < 23; ++t){
    ((float4*)lds_q)[tid] = ((const float4*)rowptr(0, t))[tid];
    __syncthreads();
    const float2* q2 = (const float2*)lds_q;
    float qs = 0.f;
    #pragma unroll
    for (int j2 = 0; j2 < 8; ++j2){
      float2 qq = q2[lane + 64*j2];
      qs += qq.x*qq.x + qq.y*qq.y;
    }
    #pragma unroll
    for (int off = 32; off; off >>= 1) qs += __shfl_xor(qs, off);
    float iqn = 1.0f / fmaxf(sqrtf(qs), 1e-12f);
    for (int u = wid; u < U; u += 4){
      float acc = 0.f;
      #pragma unroll
      for (int j2 = 0; j2 < 8; ++j2){
        uint32_t kk = lk32[u*512 + lane + 64*j2];
        float2 qq = q2[lane + 64*j2];
        acc += qq.x*bflo(kk) + qq.y*bfhi(kk);
      }
      #pragma unroll
      for (int off = 32; off; off >>= 1) acc += __shfl_xor(acc, off);
      if (lane == 0){
        float pv = (MODE == 0) ? pe[t*23 + u] : pe[(h*23 + t)*13 + u];
        lds_A[t][u] = acc * iqn * lds_ikn[u] + pv;
      }
    }
    __syncthreads();
  }

  // Phase 3: row softmax (one wave per row)
  for (int t = wid; t < 23; t += 4){
    float a = (lane < U) ? lds_A[t][lane] : -__builtin_huge_valf();
    float m = a;
    #pragma unroll
    for (int off = 32; off; off >>= 1) m = fmaxf(m, __shfl_xor(m, off));
    float e = (lane < U) ? __expf(a - m) : 0.f;
    float ssum = e;
    #pragma unroll
    for (int off = 32; off; off >>= 1) ssum += __shfl_xor(ssum, off);
    if (lane < U) lds_A[t][lane] = e / ssum;
  }
  __syncthreads();

  // Phase 4: O = A @ V, V pooled on the fly, kept in registers
  const size_t obase = (size_t)g * 23 * 1024;
  for (int c = 0; c < 4; ++c){
    int s = (c << 8) + tid;
    float vv[U];
    #pragma unroll
    for (int u = 0; u < U; ++u){
      int au, bu; pool_map<MODE>(u, au, bu);
      vv[u] = 0.5f * (rowptr(2, au)[s] + rowptr(2, bu)[s]);
    }
    #pragma unroll
    for (int t = 0; t < 23; ++t){
      float acc = 0.f;
      #pragma unroll
      for (int u = 0; u < U; ++u) acc += lds_A[t][u] * vv[u];
      O[obase + (size_t)t*1024 + s] = __float2bfloat16(acc);
    }
  }
}

// ---------------- projection GEMM: out[r][n] = sum_k O[r][k]*W[n][k] + bias[n] ----------------
// 128x128 tile, BK=64, 4 waves (2x2), 16x16x32 bf16 MFMA, global_load_lds staging.
// Output row remap: r -> (r/DIV)*5888 + CB + r%DIV (scatters into concat'd channel layout).
__global__ __launch_bounds__(256) void gemm_kernel(
    const __hip_bfloat16* __restrict__ A,
    const __hip_bfloat16* __restrict__ W,
    const float* __restrict__ bias,
    float* __restrict__ out,
    int M, int DIV, int CB)
{
  __shared__ __hip_bfloat16 lA[128*64];
  __shared__ __hip_bfloat16 lB[128*64];
  const int tid  = threadIdx.x;
  const int lane = tid & 63;
  const int tM = blockIdx.x * 128, tN = blockIdx.y * 128;
  const int wm = ((tid >> 6) >> 1) * 64, wn = ((tid >> 6) & 1) * 64;
  f32x4 acc[4][4] = {};
  const int srow = tid >> 3;         // 0..31
  const int scol = (tid & 7) * 8;    // k-chunk offset (elems)
  const __hip_bfloat16* ga = A + (size_t)(tM + srow) * 1024 + scol;
  const __hip_bfloat16* gb = W + (size_t)(tN + srow) * 1024 + scol;

  for (int k0 = 0; k0 < 1024; k0 += 64){
    #pragma unroll
    for (int q = 0; q < 4; ++q){
      __builtin_amdgcn_global_load_lds(
        (const __attribute__((address_space(1))) void*)(ga + k0 + (size_t)q*32*1024),
        (__attribute__((address_space(3))) void*)(lA + q*2048 + tid*8), 16, 0, 0);
      __builtin_amdgcn_global_load_lds(
        (const __attribute__((address_space(1))) void*)(gb + k0 + (size_t)q*32*1024),
        (__attribute__((address_space(3))) void*)(lB + q*2048 + tid*8), 16, 0, 0);
    }
    __syncthreads();
    #pragma unroll
    for (int kk = 0; kk < 2; ++kk){
      bf16x8 af[4], bfr[4];
      #pragma unroll
      for (int mi = 0; mi < 4; ++mi)
        af[mi] = *(const bf16x8*)(lA + (wm + mi*16 + (lane & 15))*64 + kk*32 + (lane >> 4)*8);
      #pragma unroll
      for (int ni = 0; ni < 4; ++ni)
        bfr[ni] = *(const bf16x8*)(lB + (wn + ni*16 + (lane & 15))*64 + kk*32 + (lane >> 4)*8);
      #pragma unroll
      for (int mi = 0; mi < 4; ++mi){
        #pragma unroll
        for (int ni = 0; ni < 4; ++ni){
          acc[mi][ni] = __builtin_amdgcn_mfma_f32_16x16x32_bf16(af[mi], bfr[ni], acc[mi][ni], 0, 0, 0);
        }
      }
    }
    __syncthreads();
  }

  #pragma unroll
  for (int mi = 0; mi < 4; ++mi){
    #pragma unroll
    for (int j = 0; j < 4; ++j){
      int r = tM + wm + mi*16 + (lane >> 4)*4 + j;
      int bq = r / DIV, rem = r % DIV;
      size_t orow = (size_t)bq * 5888 + CB + rem;
      float* po = out + orow * 1024 + tN + wn + (lane & 15);
      #pragma unroll
      for (int ni = 0; ni < 4; ++ni){
        int n = tN + wn + ni*16 + (lane & 15);
        po[ni*16] = acc[mi][ni][j] + bias[n];
      }
    }
  }
}

extern "C" void kernel_launch(void* const* d_in, const int* in_sizes, int n_in,
                              void* d_out, int out_size, void* d_ws, size_t ws_size,
                              hipStream_t stream) {
  const float* xh0  = (const float*)d_in[0];
  const float* xh1  = (const float*)d_in[1];
  const float* xh2  = (const float*)d_in[2];
  const float* xl0  = (const float*)d_in[3];
  const float* xl1  = (const float*)d_in[4];
  const float* xl2  = (const float*)d_in[5];
  const float* htab = (const float*)d_in[6];
  const float* habs = (const float*)d_in[7];
  const float* ltab = (const float*)d_in[8];
  const float* labs = (const float*)d_in[9];
  const float* hw   = (const float*)d_in[10];
  const float* hb   = (const float*)d_in[11];
  const float* lw   = (const float*)d_in[12];
  const float* lb   = (const float*)d_in[13];
  float* out = (float*)d_out;

  char* ws = (char*)d_ws;
  float* pe_h = (float*)ws;                                  // 529 f32
  float* pe_l = (float*)(ws + 2176);                         // 897 f32
  __hip_bfloat16* whb = (__hip_bfloat16*)(ws + 8192);        // 1M bf16
  __hip_bfloat16* wlb = (__hip_bfloat16*)(ws + 8192 + 2097152);
  __hip_bfloat16* Oh  = (__hip_bfloat16*)(ws + 8192 + 4194304);
  __hip_bfloat16* Ol  = Oh + (size_t)5888 * 1024;

  prep_kernel<<<8198, 256, 0, stream>>>(htab, habs, ltab, labs, hw, lw, pe_h, pe_l, whb, wlb);
  attn_kernel<0><<<256, 256, 0, stream>>>(xh0, xh1, xh2, pe_h, Oh);
  attn_kernel<1><<<768, 256, 0, stream>>>(xl0, xl1, xl2, pe_l, Ol);
  gemm_kernel<<<dim3(46, 8), 256, 0, stream>>>(Oh, whb, hb, out, 5888, 1472, 0);
  gemm_kernel<<<dim3(138, 8), 256, 0, stream>>>(Ol, wlb, lb, out, 17664, 4416, 1472);
}

// Round 2
// 250.861 us; speedup vs baseline: 2.3479x; 2.3479x over previous
//
#include <hip/hip_runtime.h>
#include <hip/hip_bf16.h>
#include <stdint.h>

#define DEV __device__ __forceinline__

typedef float f32x4 __attribute__((ext_vector_type(4)));
typedef __bf16 bf16x8 __attribute__((ext_vector_type(8)));

DEV __bf16 tobf(float x){
  union { __hip_bfloat16 s; __bf16 b; } u; u.s = __float2bfloat16(x); return u.b;
}
DEV float bf2f(__bf16 b){
  union { __bf16 b; __hip_bfloat16 s; } u; u.b = b; return __bfloat162float(u.s);
}
DEV float dot4(const float4& a, const float4& b){
  return a.x*b.x + a.y*b.y + a.z*b.z + a.w*b.w;
}
DEV bf16x8 pack8(const float4& a, const float4& b){
  bf16x8 r;
  r[0]=tobf(a.x); r[1]=tobf(a.y); r[2]=tobf(a.z); r[3]=tobf(a.w);
  r[4]=tobf(b.x); r[5]=tobf(b.y); r[6]=tobf(b.z); r[7]=tobf(b.w);
  return r;
}

// relative-coordinate values (matches reference _rel_index, f32 semantics)
DEV float relc(int j){
  if (j < 17) return (float)(j - 8);
  if (j < 22) return (float)(j - 19) * 3.4f;   // (i-2) * 17/5
  return 0.0f;
}
DEV int band_of(int t){ return t < 17 ? 0 : (t < 22 ? 1 : 2); }

// avgpool1d index map over the concatenated 23-axis -> 13 pooled slots.
template<int MODE> DEV void pool_map(int u, int& a, int& b){
  if (MODE == 0){ a = u; b = u; return; }
  if (u == 0){ a = 0; b = 0; }
  else if (u < 9){ a = 2*u - 1; b = 2*u; }
  else if (u == 9){ a = 17; b = 17; }
  else if (u < 12){ a = 2*u - 2; b = 2*u - 1; }
  else { a = 22; b = 22; }
}

DEV float interp_tab(const float* tab, int H, int h, int t, int u){
  float idx = relc(t) - relc(u) + 16.0f;
  float fl = floorf(idx);
  float ce = ceilf(idx);
  int fi = (int)fminf(fmaxf(fl, 0.f), 1088.f);
  int ci = (int)fminf(fmaxf(ce, 0.f), 1088.f);
  float w = idx - fl;
  return (1.0f - w) * tab[fi*H + h] + w * tab[ci*H + h];
}

// ---------------- prep: pos-embed tables + weight bf16 conversion ----------------
__global__ __launch_bounds__(256) void prep_kernel(
    const float* __restrict__ htab, const float* __restrict__ habs,
    const float* __restrict__ ltab, const float* __restrict__ labs,
    const float* __restrict__ hw, const float* __restrict__ lw,
    float* __restrict__ pe_h, float* __restrict__ pe_l,
    __hip_bfloat16* __restrict__ whb, __hip_bfloat16* __restrict__ wlb)
{
  int i = blockIdx.x * 256 + threadIdx.x;
  if (i < 1048576){ whb[i] = __float2bfloat16(hw[i]); return; }
  if (i < 2097152){ int k = i - 1048576; wlb[k] = __float2bfloat16(lw[k]); return; }
  int j = i - 2097152;
  if (j < 529){
    int t = j / 23, u = j % 23;
    pe_h[j] = interp_tab(htab, 1, 0, t, u) + habs[band_of(t)];
    return;
  }
  j -= 529;
  if (j < 897){
    int h = j / 299, r = j % 299, t = r / 13, u = r % 13;
    int a, b; pool_map<1>(u, a, b);
    float v = 0.5f * (interp_tab(ltab, 3, h, t, a) + interp_tab(ltab, 3, h, t, b));
    pe_l[j] = v + labs[band_of(t)*3 + h];  // pe_l[(h*23+t)*13+u]
  }
}

// ---------------- fused attention, MFMA-based ----------------
// One block per group. 4 waves k-split QK^T, LDS reduce + softmax, MFMA PV.
template<int MODE>
DEV void attn_group(int gm,
    const float* __restrict__ x0, const float* __restrict__ x1, const float* __restrict__ x2,
    const float* __restrict__ pe, __hip_bfloat16* __restrict__ Obase,
    float* Spart /*[4][32][33]*/, float* qnp /*[4][32]*/, float* knp /*[4][32]*/,
    float* iqn /*[32]*/, float* ikn /*[32]*/,
    __bf16* PH /*[32][32]*/, __bf16* PL /*[32][32]*/)
{
  constexpr int U = (MODE == 0) ? 23 : 13;
  constexpr int H = (MODE == 0) ? 1 : 3;
  int b, h, d;
  if (MODE == 0){ b = gm >> 6; h = 0; d = gm & 63; }
  else { b = gm / 192; int r = gm % 192; h = r >> 6; d = r & 63; }

  const int tid  = threadIdx.x;
  const int lane = tid & 63;
  const int w    = tid >> 6;
  const int lrow = lane & 15;
  const int kq   = lane >> 4;

  // band base pointers: sel 0=q 1=k 2=v
  auto base_of = [&](const float* xx0, const float* xx1, const float* xx2,
                     int sel, int band) -> const float* {
    if (band == 0) return xx0 + (size_t)((((sel*4 + b)*H + h)*64 + d)*17) * 1024;
    if (band == 1) return xx1 + (size_t)((((sel*4 + b)*H + h)*64 + d)*5) * 1024;
    return xx2 + (size_t)(((sel*4 + b)*H + h)*64 + d) * 1024;
  };
  const float* qb0 = base_of(x0,x1,x2,0,0); const float* qb1 = base_of(x0,x1,x2,0,1); const float* qb2 = base_of(x0,x1,x2,0,2);
  const float* kb0 = base_of(x0,x1,x2,1,0); const float* kb1 = base_of(x0,x1,x2,1,1); const float* kb2 = base_of(x0,x1,x2,1,2);
  const float* vb0 = base_of(x0,x1,x2,2,0); const float* vb1 = base_of(x0,x1,x2,2,1); const float* vb2 = base_of(x0,x1,x2,2,2);

  auto rowp = [&](const float* r0, const float* r1, const float* r2, int t) -> const float* {
    if (t < 17) return r0 + (size_t)t * 1024;
    if (t < 22) return r1 + (size_t)(t - 17) * 1024;
    return r2;
  };

  // ---- phase 1: QK^T, k-split across 4 waves ----
  // per-lane row pointers & validity
  const float* qr[2]; bool qv[2];
  #pragma unroll
  for (int mi = 0; mi < 2; ++mi){
    int t = mi*16 + lrow;
    qv[mi] = (t < 23);
    qr[mi] = qv[mi] ? rowp(qb0,qb1,qb2,t) : qb0;
  }
  const float* krA[2]; const float* krB[2]; bool kv[2];
  #pragma unroll
  for (int ni = 0; ni < 2; ++ni){
    int u = ni*16 + lrow;
    kv[ni] = (u < U);
    int au, bu; pool_map<MODE>(kv[ni] ? u : 0, au, bu);
    krA[ni] = rowp(kb0,kb1,kb2,au);
    krB[ni] = rowp(kb0,kb1,kb2,bu);
  }

  f32x4 acc[2][2] = {};
  float qss[2] = {0.f, 0.f}, kss[2] = {0.f, 0.f};
  const int sbase = w*256 + kq*8;

  #pragma unroll 2
  for (int kk = 0; kk < 8; ++kk){
    const int s = sbase + kk*32;
    bf16x8 qf[2], kf[2];
    #pragma unroll
    for (int mi = 0; mi < 2; ++mi){
      float4 v0 = {0,0,0,0}, v1 = {0,0,0,0};
      if (qv[mi]){
        v0 = *(const float4*)(qr[mi] + s);
        v1 = *(const float4*)(qr[mi] + s + 4);
      }
      qss[mi] += dot4(v0,v0) + dot4(v1,v1);
      qf[mi] = pack8(v0, v1);
    }
    #pragma unroll
    for (int ni = 0; ni < 2; ++ni){
      float4 v0 = {0,0,0,0}, v1 = {0,0,0,0};
      if ((MODE == 0 || ni == 0) && kv[ni]){
        if (MODE == 0){
          v0 = *(const float4*)(krA[ni] + s);
          v1 = *(const float4*)(krA[ni] + s + 4);
        } else {
          float4 a0 = *(const float4*)(krA[ni] + s);
          float4 a1 = *(const float4*)(krA[ni] + s + 4);
          float4 b0 = *(const float4*)(krB[ni] + s);
          float4 b1 = *(const float4*)(krB[ni] + s + 4);
          v0.x = 0.5f*(a0.x+b0.x); v0.y = 0.5f*(a0.y+b0.y); v0.z = 0.5f*(a0.z+b0.z); v0.w = 0.5f*(a0.w+b0.w);
          v1.x = 0.5f*(a1.x+b1.x); v1.y = 0.5f*(a1.y+b1.y); v1.z = 0.5f*(a1.z+b1.z); v1.w = 0.5f*(a1.w+b1.w);
        }
      }
      kss[ni] += dot4(v0,v0) + dot4(v1,v1);
      kf[ni] = pack8(v0, v1);
    }
    #pragma unroll
    for (int mi = 0; mi < 2; ++mi){
      #pragma unroll
      for (int ni = 0; ni < 2; ++ni){
        if (MODE == 0 || ni == 0)
          acc[mi][ni] = __builtin_amdgcn_mfma_f32_16x16x32_bf16(qf[mi], kf[ni], acc[mi][ni], 0, 0, 0);
      }
    }
  }

  // reduce sumsq across the 4 k-quarters (lanes xor 16,32), publish per-wave partials
  #pragma unroll
  for (int i = 0; i < 2; ++i){
    qss[i] += __shfl_xor(qss[i], 16); qss[i] += __shfl_xor(qss[i], 32);
    kss[i] += __shfl_xor(kss[i], 16); kss[i] += __shfl_xor(kss[i], 32);
  }
  if (lane < 16){
    qnp[w*32 + lane]      = qss[0];
    qnp[w*32 + 16 + lane] = qss[1];
    knp[w*32 + lane]      = kss[0];
    knp[w*32 + 16 + lane] = kss[1];
  }
  // publish partial scores (row stride 33 to avoid bank conflicts)
  #pragma unroll
  for (int mi = 0; mi < 2; ++mi)
    #pragma unroll
    for (int ni = 0; ni < 2; ++ni)
      #pragma unroll
      for (int j = 0; j < 4; ++j)
        Spart[w*1056 + (mi*16 + kq*4 + j)*33 + ni*16 + lrow] = acc[mi][ni][j];
  __syncthreads();

  // ---- phase 2a: norms ----
  if (tid < 32){
    float s = qnp[tid] + qnp[32+tid] + qnp[64+tid] + qnp[96+tid];
    iqn[tid] = 1.0f / fmaxf(sqrtf(s), 1e-12f);
  } else if (tid < 64){
    int c = tid - 32;
    float s = knp[c] + knp[32+c] + knp[64+c] + knp[96+c];
    ikn[c] = 1.0f / fmaxf(sqrtf(s), 1e-12f);
  }
  __syncthreads();

  // ---- phase 2b: reduce partials, scale, +pe, softmax (8 lanes per row) ----
  {
    int r  = tid >> 3;
    int c0 = (tid & 7) * 4;
    float aiq = iqn[r];
    float vals[4];
    #pragma unroll
    for (int j = 0; j < 4; ++j){
      int c = c0 + j;
      float sv = Spart[r*33 + c] + Spart[1056 + r*33 + c] + Spart[2112 + r*33 + c] + Spart[3168 + r*33 + c];
      if (r < 23 && c < U){
        float pv = (MODE == 0) ? pe[r*23 + c] : pe[(h*23 + r)*13 + c];
        vals[j] = sv * aiq * ikn[c] + pv;
      } else vals[j] = -3.0e38f;
    }
    float m = fmaxf(fmaxf(vals[0], vals[1]), fmaxf(vals[2], vals[3]));
    m = fmaxf(m, __shfl_xor(m, 1)); m = fmaxf(m, __shfl_xor(m, 2)); m = fmaxf(m, __shfl_xor(m, 4));
    float e[4], ssum = 0.f;
    #pragma unroll
    for (int j = 0; j < 4; ++j){ e[j] = __expf(vals[j] - m); ssum += e[j]; }
    ssum += __shfl_xor(ssum, 1); ssum += __shfl_xor(ssum, 2); ssum += __shfl_xor(ssum, 4);
    float inv = 1.0f / ssum;
    #pragma unroll
    for (int j = 0; j < 4; ++j){
      float p = e[j] * inv;
      __bf16 ph = tobf(p);
      PH[r*32 + c0 + j] = ph;
      PL[r*32 + c0 + j] = tobf(p - bf2f(ph));
    }
  }
  __syncthreads();

  // ---- phase 3: O = P @ V via MFMA (K-dim = padded u), hi/lo split for ~f32 precision ----
  bf16x8 pfh[2], pfl[2];
  pfh[0] = *(const bf16x8*)(PH + lrow*32 + kq*8);
  pfh[1] = *(const bf16x8*)(PH + (16 + lrow)*32 + kq*8);
  pfl[0] = *(const bf16x8*)(PL + lrow*32 + kq*8);
  pfl[1] = *(const bf16x8*)(PL + (16 + lrow)*32 + kq*8);

  const float* va[8]; const float* vbp[8]; bool uval[8];
  #pragma unroll
  for (int j = 0; j < 8; ++j){
    int u = kq*8 + j;
    uval[j] = (u < U);
    int au, bu; pool_map<MODE>(uval[j] ? u : 0, au, bu);
    va[j]  = rowp(vb0,vb1,vb2,au);
    vbp[j] = rowp(vb0,vb1,vb2,bu);
  }

  __hip_bfloat16* Og = (__hip_bfloat16*)Obase + (size_t)gm * 23 * 1024;

  #pragma unroll 2
  for (int nt = 0; nt < 16; ++nt){
    const int sb = w*256 + nt*16 + lrow;
    bf16x8 vfh, vfl;
    #pragma unroll
    for (int j = 0; j < 8; ++j){
      float x = 0.f;
      if (uval[j]){
        if (MODE == 0) x = va[j][sb];
        else           x = 0.5f * (va[j][sb] + vbp[j][sb]);
      }
      __bf16 hb = tobf(x);
      vfh[j] = hb;
      vfl[j] = tobf(x - bf2f(hb));
    }
    f32x4 o0 = {0,0,0,0}, o1 = {0,0,0,0};
    o0 = __builtin_amdgcn_mfma_f32_16x16x32_bf16(pfh[0], vfh, o0, 0, 0, 0);
    o0 = __builtin_amdgcn_mfma_f32_16x16x32_bf16(pfh[0], vfl, o0, 0, 0, 0);
    o0 = __builtin_amdgcn_mfma_f32_16x16x32_bf16(pfl[0], vfh, o0, 0, 0, 0);
    o1 = __builtin_amdgcn_mfma_f32_16x16x32_bf16(pfh[1], vfh, o1, 0, 0, 0);
    o1 = __builtin_amdgcn_mfma_f32_16x16x32_bf16(pfh[1], vfl, o1, 0, 0, 0);
    o1 = __builtin_amdgcn_mfma_f32_16x16x32_bf16(pfl[1], vfh, o1, 0, 0, 0);
    #pragma unroll
    for (int j = 0; j < 4; ++j){
      int t0 = kq*4 + j;
      Og[(size_t)t0*1024 + sb] = __float2bfloat16(o0[j]);
      int t1 = 16 + kq*4 + j;
      if (t1 < 23) Og[(size_t)t1*1024 + sb] = __float2bfloat16(o1[j]);
    }
  }
}

__global__ __launch_bounds__(256) void attn_all(
    const float* __restrict__ xh0, const float* __restrict__ xh1, const float* __restrict__ xh2,
    const float* __restrict__ xl0, const float* __restrict__ xl1, const float* __restrict__ xl2,
    const float* __restrict__ pe_h, const float* __restrict__ pe_l,
    __hip_bfloat16* __restrict__ Oh, __hip_bfloat16* __restrict__ Ol)
{
  __shared__ __align__(16) float Spart[4*32*33];
  __shared__ float qnp[4*32], knp[4*32], iqn[32], ikn[32];
  __shared__ __align__(16) __bf16 PH[32*32], PL[32*32];

  int bid = blockIdx.x;
  if (bid < 256)
    attn_group<0>(bid, xh0, xh1, xh2, pe_h, Oh, Spart, qnp, knp, iqn, ikn, PH, PL);
  else
    attn_group<1>(bid - 256, xl0, xl1, xl2, pe_l, Ol, Spart, qnp, knp, iqn, ikn, PH, PL);
}

// ---------------- projection GEMM (unchanged from round 0) ----------------
__global__ __launch_bounds__(256) void gemm_kernel(
    const __hip_bfloat16* __restrict__ A,
    const __hip_bfloat16* __restrict__ W,
    const float* __restrict__ bias,
    float* __restrict__ out,
    int M, int DIV, int CB)
{
  __shared__ __hip_bfloat16 lA[128*64];
  __shared__ __hip_bfloat16 lB[128*64];
  const int tid  = threadIdx.x;
  const int lane = tid & 63;
  const int tM = blockIdx.x * 128, tN = blockIdx.y * 128;
  const int wm = ((tid >> 6) >> 1) * 64, wn = ((tid >> 6) & 1) * 64;
  f32x4 acc[4][4] = {};
  const int srow = tid >> 3;
  const int scol = (tid & 7) * 8;
  const __hip_bfloat16* ga = A + (size_t)(tM + srow) * 1024 + scol;
  const __hip_bfloat16* gb = W + (size_t)(tN + srow) * 1024 + scol;

  for (int k0 = 0; k0 < 1024; k0 += 64){
    #pragma unroll
    for (int q = 0; q < 4; ++q){
      __builtin_amdgcn_global_load_lds(
        (const __attribute__((address_space(1))) void*)(ga + k0 + (size_t)q*32*1024),
        (__attribute__((address_space(3))) void*)(lA + q*2048 + tid*8), 16, 0, 0);
      __builtin_amdgcn_global_load_lds(
        (const __attribute__((address_space(1))) void*)(gb + k0 + (size_t)q*32*1024),
        (__attribute__((address_space(3))) void*)(lB + q*2048 + tid*8), 16, 0, 0);
    }
    __syncthreads();
    #pragma unroll
    for (int kk = 0; kk < 2; ++kk){
      bf16x8 af[4], bfr[4];
      #pragma unroll
      for (int mi = 0; mi < 4; ++mi)
        af[mi] = *(const bf16x8*)(lA + (wm + mi*16 + (lane & 15))*64 + kk*32 + (lane >> 4)*8);
      #pragma unroll
      for (int ni = 0; ni < 4; ++ni)
        bfr[ni] = *(const bf16x8*)(lB + (wn + ni*16 + (lane & 15))*64 + kk*32 + (lane >> 4)*8);
      #pragma unroll
      for (int mi = 0; mi < 4; ++mi){
        #pragma unroll
        for (int ni = 0; ni < 4; ++ni){
          acc[mi][ni] = __builtin_amdgcn_mfma_f32_16x16x32_bf16(af[mi], bfr[ni], acc[mi][ni], 0, 0, 0);
        }
      }
    }
    __syncthreads();
  }

  #pragma unroll
  for (int mi = 0; mi < 4; ++mi){
    #pragma unroll
    for (int j = 0; j < 4; ++j){
      int r = tM + wm + mi*16 + (lane >> 4)*4 + j;
      int bq = r / DIV, rem = r % DIV;
      size_t orow = (size_t)bq * 5888 + CB + rem;
      float* po = out + orow * 1024 + tN + wn + (lane & 15);
      #pragma unroll
      for (int ni = 0; ni < 4; ++ni){
        int n = tN + wn + ni*16 + (lane & 15);
        po[ni*16] = acc[mi][ni][j] + bias[n];
      }
    }
  }
}

extern "C" void kernel_launch(void* const* d_in, const int* in_sizes, int n_in,
                              void* d_out, int out_size, void* d_ws, size_t ws_size,
                              hipStream_t stream) {
  const float* xh0  = (const float*)d_in[0];
  const float* xh1  = (const float*)d_in[1];
  const float* xh2  = (const float*)d_in[2];
  const float* xl0  = (const float*)d_in[3];
  const float* xl1  = (const float*)d_in[4];
  const float* xl2  = (const float*)d_in[5];
  const float* htab = (const float*)d_in[6];
  const float* habs = (const float*)d_in[7];
  const float* ltab = (const float*)d_in[8];
  const float* labs = (const float*)d_in[9];
  const float* hw   = (const float*)d_in[10];
  const float* hb   = (const float*)d_in[11];
  const float* lw   = (const float*)d_in[12];
  const float* lb   = (const float*)d_in[13];
  float* out = (float*)d_out;

  char* ws = (char*)d_ws;
  float* pe_h = (float*)ws;                                  // 529 f32
  float* pe_l = (float*)(ws + 2176);                         // 897 f32
  __hip_bfloat16* whb = (__hip_bfloat16*)(ws + 8192);        // 1M bf16
  __hip_bfloat16* wlb = (__hip_bfloat16*)(ws + 8192 + 2097152);
  __hip_bfloat16* Oh  = (__hip_bfloat16*)(ws + 8192 + 4194304);
  __hip_bfloat16* Ol  = Oh + (size_t)5888 * 1024;

  prep_kernel<<<8198, 256, 0, stream>>>(htab, habs, ltab, labs, hw, lw, pe_h, pe_l, whb, wlb);
  attn_all<<<1024, 256, 0, stream>>>(xh0, xh1, xh2, xl0, xl1, xl2, pe_h, pe_l, Oh, Ol);
  gemm_kernel<<<dim3(46, 8), 256, 0, stream>>>(Oh, whb, hb, out, 5888, 1472, 0);
  gemm_kernel<<<dim3(138, 8), 256, 0, stream>>>(Ol, wlb, lb, out, 17664, 4416, 1472);
}

// Round 3
// 196.861 us; speedup vs baseline: 2.9919x; 1.2743x over previous
//
#include <hip/hip_runtime.h>
#include <hip/hip_bf16.h>
#include <stdint.h>

#define DEV __device__ __forceinline__

typedef float f32x4 __attribute__((ext_vector_type(4)));
typedef __bf16 bf16x8 __attribute__((ext_vector_type(8)));

DEV __bf16 tobf(float x){
  union { __hip_bfloat16 s; __bf16 b; } u; u.s = __float2bfloat16(x); return u.b;
}
DEV float dot4(const float4& a, const float4& b){
  return a.x*b.x + a.y*b.y + a.z*b.z + a.w*b.w;
}
DEV bf16x8 pack8(const float4& a, const float4& b){
  bf16x8 r;
  r[0]=tobf(a.x); r[1]=tobf(a.y); r[2]=tobf(a.z); r[3]=tobf(a.w);
  r[4]=tobf(b.x); r[5]=tobf(b.y); r[6]=tobf(b.z); r[7]=tobf(b.w);
  return r;
}
DEV uint32_t f2bf2(float x, float y){
  union { __hip_bfloat16 b[2]; uint32_t u; } cv;
  cv.b[0] = __float2bfloat16(x); cv.b[1] = __float2bfloat16(y);
  return cv.u;
}

// relative-coordinate values (matches reference _rel_index, f32 semantics)
DEV float relc(int j){
  if (j < 17) return (float)(j - 8);
  if (j < 22) return (float)(j - 19) * 3.4f;   // (i-2) * 17/5
  return 0.0f;
}
DEV int band_of(int t){ return t < 17 ? 0 : (t < 22 ? 1 : 2); }

// avgpool1d index map over the concatenated 23-axis -> 13 pooled slots.
template<int MODE> DEV void pool_map(int u, int& a, int& b){
  if (MODE == 0){ a = u; b = u; return; }
  if (u == 0){ a = 0; b = 0; }
  else if (u < 9){ a = 2*u - 1; b = 2*u; }
  else if (u == 9){ a = 17; b = 17; }
  else if (u < 12){ a = 2*u - 2; b = 2*u - 1; }
  else { a = 22; b = 22; }
}

DEV float interp_tab(const float* tab, int H, int h, int t, int u){
  float idx = relc(t) - relc(u) + 16.0f;
  float fl = floorf(idx);
  float ce = ceilf(idx);
  int fi = (int)fminf(fmaxf(fl, 0.f), 1088.f);
  int ci = (int)fminf(fmaxf(ce, 0.f), 1088.f);
  float w = idx - fl;
  return (1.0f - w) * tab[fi*H + h] + w * tab[ci*H + h];
}

// ---------------- prep: pos-embed tables + weight bf16 conversion ----------------
__global__ __launch_bounds__(256) void prep_kernel(
    const float* __restrict__ htab, const float* __restrict__ habs,
    const float* __restrict__ ltab, const float* __restrict__ labs,
    const float* __restrict__ hw, const float* __restrict__ lw,
    float* __restrict__ pe_h, float* __restrict__ pe_l,
    __hip_bfloat16* __restrict__ whb, __hip_bfloat16* __restrict__ wlb)
{
  int i = blockIdx.x * 256 + threadIdx.x;
  if (i < 1048576){ whb[i] = __float2bfloat16(hw[i]); return; }
  if (i < 2097152){ int k = i - 1048576; wlb[k] = __float2bfloat16(lw[k]); return; }
  int j = i - 2097152;
  if (j < 529){
    int t = j / 23, u = j % 23;
    pe_h[j] = interp_tab(htab, 1, 0, t, u) + habs[band_of(t)];
    return;
  }
  j -= 529;
  if (j < 897){
    int h = j / 299, r = j % 299, t = r / 13, u = r % 13;
    int a, b; pool_map<1>(u, a, b);
    float v = 0.5f * (interp_tab(ltab, 3, h, t, a) + interp_tab(ltab, 3, h, t, b));
    pe_l[j] = v + labs[band_of(t)*3 + h];  // pe_l[(h*23+t)*13+u]
  }
}

// ---------------- QK^T partial: one block per (group, s-half) ----------------
template<int MODE>
DEV void qk_group(int gm, int hh,
    const float* __restrict__ x0, const float* __restrict__ x1, const float* __restrict__ x2,
    float* __restrict__ SpB,
    float* Spart /*[4][32][33]*/, float* qnp /*[4][32]*/, float* knp /*[4][32]*/)
{
  constexpr int U = (MODE == 0) ? 23 : 13;
  constexpr int H = (MODE == 0) ? 1 : 3;
  int b, h, d;
  if (MODE == 0){ b = gm >> 6; h = 0; d = gm & 63; }
  else { b = gm / 192; int r = gm % 192; h = r >> 6; d = r & 63; }

  const int tid  = threadIdx.x;
  const int lane = tid & 63;
  const int w    = tid >> 6;
  const int lrow = lane & 15;
  const int kq   = lane >> 4;

  auto base_of = [&](int sel, int band) -> const float* {
    if (band == 0) return x0 + (size_t)((((sel*4 + b)*H + h)*64 + d)*17) * 1024;
    if (band == 1) return x1 + (size_t)((((sel*4 + b)*H + h)*64 + d)*5) * 1024;
    return x2 + (size_t)(((sel*4 + b)*H + h)*64 + d) * 1024;
  };
  const float* qb0 = base_of(0,0); const float* qb1 = base_of(0,1); const float* qb2 = base_of(0,2);
  const float* kb0 = base_of(1,0); const float* kb1 = base_of(1,1); const float* kb2 = base_of(1,2);

  auto rowp = [&](const float* r0, const float* r1, const float* r2, int t) -> const float* {
    if (t < 17) return r0 + (size_t)t * 1024;
    if (t < 22) return r1 + (size_t)(t - 17) * 1024;
    return r2;
  };

  const float* qr[2]; bool qv[2];
  #pragma unroll
  for (int mi = 0; mi < 2; ++mi){
    int t = mi*16 + lrow;
    qv[mi] = (t < 23);
    qr[mi] = qv[mi] ? rowp(qb0,qb1,qb2,t) : qb0;
  }
  const float* krA[2]; const float* krB[2]; bool kv[2];
  #pragma unroll
  for (int ni = 0; ni < 2; ++ni){
    int u = ni*16 + lrow;
    kv[ni] = (u < U);
    int au, bu; pool_map<MODE>(kv[ni] ? u : 0, au, bu);
    krA[ni] = rowp(kb0,kb1,kb2,au);
    krB[ni] = rowp(kb0,kb1,kb2,bu);
  }

  f32x4 acc[2][2] = {};
  float qss[2] = {0.f, 0.f}, kss[2] = {0.f, 0.f};
  const int sbase = hh*512 + w*128 + kq*8;

  #pragma unroll 2
  for (int kk = 0; kk < 4; ++kk){
    const int s = sbase + kk*32;
    bf16x8 qf[2], kf[2];
    #pragma unroll
    for (int mi = 0; mi < 2; ++mi){
      float4 v0 = {0,0,0,0}, v1 = {0,0,0,0};
      if (qv[mi]){
        v0 = *(const float4*)(qr[mi] + s);
        v1 = *(const float4*)(qr[mi] + s + 4);
      }
      qss[mi] += dot4(v0,v0) + dot4(v1,v1);
      qf[mi] = pack8(v0, v1);
    }
    #pragma unroll
    for (int ni = 0; ni < 2; ++ni){
      float4 v0 = {0,0,0,0}, v1 = {0,0,0,0};
      if ((MODE == 0 || ni == 0) && kv[ni]){
        if (MODE == 0){
          v0 = *(const float4*)(krA[ni] + s);
          v1 = *(const float4*)(krA[ni] + s + 4);
        } else {
          float4 a0 = *(const float4*)(krA[ni] + s);
          float4 a1 = *(const float4*)(krA[ni] + s + 4);
          float4 b0 = *(const float4*)(krB[ni] + s);
          float4 b1 = *(const float4*)(krB[ni] + s + 4);
          v0.x = 0.5f*(a0.x+b0.x); v0.y = 0.5f*(a0.y+b0.y); v0.z = 0.5f*(a0.z+b0.z); v0.w = 0.5f*(a0.w+b0.w);
          v1.x = 0.5f*(a1.x+b1.x); v1.y = 0.5f*(a1.y+b1.y); v1.z = 0.5f*(a1.z+b1.z); v1.w = 0.5f*(a1.w+b1.w);
        }
      }
      kss[ni] += dot4(v0,v0) + dot4(v1,v1);
      kf[ni] = pack8(v0, v1);
    }
    #pragma unroll
    for (int mi = 0; mi < 2; ++mi){
      #pragma unroll
      for (int ni = 0; ni < 2; ++ni){
        if (MODE == 0 || ni == 0)
          acc[mi][ni] = __builtin_amdgcn_mfma_f32_16x16x32_bf16(qf[mi], kf[ni], acc[mi][ni], 0, 0, 0);
      }
    }
  }

  #pragma unroll
  for (int i = 0; i < 2; ++i){
    qss[i] += __shfl_xor(qss[i], 16); qss[i] += __shfl_xor(qss[i], 32);
    kss[i] += __shfl_xor(kss[i], 16); kss[i] += __shfl_xor(kss[i], 32);
  }
  if (lane < 16){
    qnp[w*32 + lane]      = qss[0];
    qnp[w*32 + 16 + lane] = qss[1];
    knp[w*32 + lane]      = kss[0];
    knp[w*32 + 16 + lane] = kss[1];
  }
  #pragma unroll
  for (int mi = 0; mi < 2; ++mi)
    #pragma unroll
    for (int ni = 0; ni < 2; ++ni)
      #pragma unroll
      for (int j = 0; j < 4; ++j)
        Spart[w*1056 + (mi*16 + kq*4 + j)*33 + ni*16 + lrow] = acc[mi][ni][j];
  __syncthreads();

  // emit per-block partials: S[32][32] + qn[32] + kn[32]  (1088 floats)
  if (tid < 32){
    SpB[1024 + tid] = qnp[tid] + qnp[32+tid] + qnp[64+tid] + qnp[96+tid];
  } else if (tid < 64){
    int c = tid - 32;
    SpB[1056 + c] = knp[c] + knp[32+c] + knp[64+c] + knp[96+c];
  }
  {
    int r  = tid >> 3;
    int c0 = (tid & 7) * 4;
    float4 o;
    o.x = Spart[r*33+c0+0] + Spart[1056+r*33+c0+0] + Spart[2112+r*33+c0+0] + Spart[3168+r*33+c0+0];
    o.y = Spart[r*33+c0+1] + Spart[1056+r*33+c0+1] + Spart[2112+r*33+c0+1] + Spart[3168+r*33+c0+1];
    o.z = Spart[r*33+c0+2] + Spart[1056+r*33+c0+2] + Spart[2112+r*33+c0+2] + Spart[3168+r*33+c0+2];
    o.w = Spart[r*33+c0+3] + Spart[1056+r*33+c0+3] + Spart[2112+r*33+c0+3] + Spart[3168+r*33+c0+3];
    *(float4*)(SpB + r*32 + c0) = o;
  }
}

__global__ __launch_bounds__(256) void qk_partial(
    const float* __restrict__ xh0, const float* __restrict__ xh1, const float* __restrict__ xh2,
    const float* __restrict__ xl0, const float* __restrict__ xl1, const float* __restrict__ xl2,
    float* __restrict__ Sp)
{
  __shared__ __align__(16) float Spart[4*32*33];
  __shared__ float qnp[4*32], knp[4*32];
  int bid = blockIdx.x;
  int g = bid >> 1, hh = bid & 1;
  float* SpB = Sp + (size_t)bid * 1088;
  if (g < 256) qk_group<0>(g, hh, xh0, xh1, xh2, SpB, Spart, qnp, knp);
  else         qk_group<1>(g - 256, hh, xl0, xl1, xl2, SpB, Spart, qnp, knp);
}

// ---------------- finalize: combine halves, l2norm scale, +pe, softmax -> P ----------------
__global__ __launch_bounds__(256) void attn_finalize(
    const float* __restrict__ Sp, const float* __restrict__ pe_h, const float* __restrict__ pe_l,
    float* __restrict__ P)
{
  int g = blockIdx.x;
  int tid = threadIdx.x;
  int r = tid >> 3, c0 = (tid & 7) * 4;
  const float* A = Sp + (size_t)(2*g) * 1088;
  const float* B = A + 1088;
  float qn = A[1024 + r] + B[1024 + r];
  float iqn = 1.0f / fmaxf(sqrtf(qn), 1e-12f);
  int U, h;
  if (g < 256){ U = 23; h = 0; }
  else { U = 13; h = ((g - 256) % 192) >> 6; }
  float vals[4];
  #pragma unroll
  for (int j = 0; j < 4; ++j){
    int c = c0 + j;
    float sv = A[r*32 + c] + B[r*32 + c];
    float kn = A[1056 + c] + B[1056 + c];
    float ikn = 1.0f / fmaxf(sqrtf(kn), 1e-12f);
    bool valid = (r < 23) && (c < U);
    if (valid){
      float pv = (g < 256) ? pe_h[r*23 + c] : pe_l[(h*23 + r)*13 + c];
      vals[j] = sv * iqn * ikn + pv;
    } else vals[j] = -3.0e38f;
  }
  float m = fmaxf(fmaxf(vals[0], vals[1]), fmaxf(vals[2], vals[3]));
  m = fmaxf(m, __shfl_xor(m, 1)); m = fmaxf(m, __shfl_xor(m, 2)); m = fmaxf(m, __shfl_xor(m, 4));
  float e[4], ssum = 0.f;
  #pragma unroll
  for (int j = 0; j < 4; ++j){ e[j] = __expf(vals[j] - m); ssum += e[j]; }
  ssum += __shfl_xor(ssum, 1); ssum += __shfl_xor(ssum, 2); ssum += __shfl_xor(ssum, 4);
  float inv = 1.0f / ssum;
  if (r < 23){
    #pragma unroll
    for (int j = 0; j < 4; ++j){
      int c = c0 + j;
      bool valid = (c < U);
      P[(size_t)g*736 + r*32 + c] = valid ? e[j] * inv : 0.f;
    }
  }
}

// ---------------- PV: streaming, one block per (group, s-half) ----------------
template<int MODE>
DEV void pv_group(int gm, int sh,
    const float* __restrict__ x0, const float* __restrict__ x1, const float* __restrict__ x2,
    const float* __restrict__ Pg, __hip_bfloat16* __restrict__ Og, float* lds_p)
{
  constexpr int U  = (MODE == 0) ? 23 : 13;
  constexpr int UP = (MODE == 0) ? 24 : 16;
  constexpr int H  = (MODE == 0) ? 1 : 3;
  int b, h, d;
  if (MODE == 0){ b = gm >> 6; h = 0; d = gm & 63; }
  else { b = gm / 192; int r = gm % 192; h = r >> 6; d = r & 63; }
  const int tid = threadIdx.x;

  if (tid < 184) *(float4*)(lds_p + tid*4) = *(const float4*)(Pg + tid*4);
  __syncthreads();

  const float* vb0 = x0 + (size_t)((((2*4 + b)*H + h)*64 + d)*17) * 1024;
  const float* vb1 = x1 + (size_t)((((2*4 + b)*H + h)*64 + d)*5) * 1024;
  const float* vb2 = x2 + (size_t)(((2*4 + b)*H + h)*64 + d) * 1024;
  auto rowp = [&](int t) -> const float* {
    if (t < 17) return vb0 + (size_t)t * 1024;
    if (t < 22) return vb1 + (size_t)(t - 17) * 1024;
    return vb2;
  };

  const int s0 = sh*512 + tid*2;
  float2 vv[UP];
  #pragma unroll
  for (int u = 0; u < UP; ++u){
    if (u < U){
      int au, bu; pool_map<MODE>(u, au, bu);
      float2 a = *(const float2*)(rowp(au) + s0);
      if (MODE == 0) vv[u] = a;
      else {
        float2 c = *(const float2*)(rowp(bu) + s0);
        vv[u].x = 0.5f*(a.x + c.x); vv[u].y = 0.5f*(a.y + c.y);
      }
    } else { vv[u].x = 0.f; vv[u].y = 0.f; }
  }

  #pragma unroll 2
  for (int t = 0; t < 23; ++t){
    float ax = 0.f, ay = 0.f;
    #pragma unroll
    for (int u4 = 0; u4 < UP/4; ++u4){
      float4 p = *(const float4*)(lds_p + t*32 + u4*4);
      ax += p.x*vv[u4*4+0].x + p.y*vv[u4*4+1].x + p.z*vv[u4*4+2].x + p.w*vv[u4*4+3].x;
      ay += p.x*vv[u4*4+0].y + p.y*vv[u4*4+1].y + p.z*vv[u4*4+2].y + p.w*vv[u4*4+3].y;
    }
    *(uint32_t*)((__hip_bfloat16*)Og + (size_t)t*1024 + s0) = f2bf2(ax, ay);
  }
}

__global__ __launch_bounds__(256) void pv_all(
    const float* __restrict__ xh0, const float* __restrict__ xh1, const float* __restrict__ xh2,
    const float* __restrict__ xl0, const float* __restrict__ xl1, const float* __restrict__ xl2,
    const float* __restrict__ P,
    __hip_bfloat16* __restrict__ Oh, __hip_bfloat16* __restrict__ Ol)
{
  __shared__ __align__(16) float lds_p[736];
  int bid = blockIdx.x;
  int g = bid >> 1, sh = bid & 1;
  if (g < 256) pv_group<0>(g, sh, xh0, xh1, xh2, P + (size_t)g*736, Oh + (size_t)g*23552, lds_p);
  else {
    int gm = g - 256;
    pv_group<1>(gm, sh, xl0, xl1, xl2, P + (size_t)g*736, Ol + (size_t)gm*23552, lds_p);
  }
}

// ---------------- projection GEMM (unchanged) ----------------
__global__ __launch_bounds__(256) void gemm_kernel(
    const __hip_bfloat16* __restrict__ A,
    const __hip_bfloat16* __restrict__ W,
    const float* __restrict__ bias,
    float* __restrict__ out,
    int M, int DIV, int CB)
{
  __shared__ __hip_bfloat16 lA[128*64];
  __shared__ __hip_bfloat16 lB[128*64];
  const int tid  = threadIdx.x;
  const int lane = tid & 63;
  const int tM = blockIdx.x * 128, tN = blockIdx.y * 128;
  const int wm = ((tid >> 6) >> 1) * 64, wn = ((tid >> 6) & 1) * 64;
  f32x4 acc[4][4] = {};
  const int srow = tid >> 3;
  const int scol = (tid & 7) * 8;
  const __hip_bfloat16* ga = A + (size_t)(tM + srow) * 1024 + scol;
  const __hip_bfloat16* gb = W + (size_t)(tN + srow) * 1024 + scol;

  for (int k0 = 0; k0 < 1024; k0 += 64){
    #pragma unroll
    for (int q = 0; q < 4; ++q){
      __builtin_amdgcn_global_load_lds(
        (const __attribute__((address_space(1))) void*)(ga + k0 + (size_t)q*32*1024),
        (__attribute__((address_space(3))) void*)(lA + q*2048 + tid*8), 16, 0, 0);
      __builtin_amdgcn_global_load_lds(
        (const __attribute__((address_space(1))) void*)(gb + k0 + (size_t)q*32*1024),
        (__attribute__((address_space(3))) void*)(lB + q*2048 + tid*8), 16, 0, 0);
    }
    __syncthreads();
    #pragma unroll
    for (int kk = 0; kk < 2; ++kk){
      bf16x8 af[4], bfr[4];
      #pragma unroll
      for (int mi = 0; mi < 4; ++mi)
        af[mi] = *(const bf16x8*)(lA + (wm + mi*16 + (lane & 15))*64 + kk*32 + (lane >> 4)*8);
      #pragma unroll
      for (int ni = 0; ni < 4; ++ni)
        bfr[ni] = *(const bf16x8*)(lB + (wn + ni*16 + (lane & 15))*64 + kk*32 + (lane >> 4)*8);
      #pragma unroll
      for (int mi = 0; mi < 4; ++mi){
        #pragma unroll
        for (int ni = 0; ni < 4; ++ni){
          acc[mi][ni] = __builtin_amdgcn_mfma_f32_16x16x32_bf16(af[mi], bfr[ni], acc[mi][ni], 0, 0, 0);
        }
      }
    }
    __syncthreads();
  }

  #pragma unroll
  for (int mi = 0; mi < 4; ++mi){
    #pragma unroll
    for (int j = 0; j < 4; ++j){
      int r = tM + wm + mi*16 + (lane >> 4)*4 + j;
      int bq = r / DIV, rem = r % DIV;
      size_t orow = (size_t)bq * 5888 + CB + rem;
      float* po = out + orow * 1024 + tN + wn + (lane & 15);
      #pragma unroll
      for (int ni = 0; ni < 4; ++ni){
        int n = tN + wn + ni*16 + (lane & 15);
        po[ni*16] = acc[mi][ni][j] + bias[n];
      }
    }
  }
}

extern "C" void kernel_launch(void* const* d_in, const int* in_sizes, int n_in,
                              void* d_out, int out_size, void* d_ws, size_t ws_size,
                              hipStream_t stream) {
  const float* xh0  = (const float*)d_in[0];
  const float* xh1  = (const float*)d_in[1];
  const float* xh2  = (const float*)d_in[2];
  const float* xl0  = (const float*)d_in[3];
  const float* xl1  = (const float*)d_in[4];
  const float* xl2  = (const float*)d_in[5];
  const float* htab = (const float*)d_in[6];
  const float* habs = (const float*)d_in[7];
  const float* ltab = (const float*)d_in[8];
  const float* labs = (const float*)d_in[9];
  const float* hw   = (const float*)d_in[10];
  const float* hb   = (const float*)d_in[11];
  const float* lw   = (const float*)d_in[12];
  const float* lb   = (const float*)d_in[13];
  float* out = (float*)d_out;

  char* ws = (char*)d_ws;
  float* pe_h = (float*)ws;                                  // 529 f32
  float* pe_l = (float*)(ws + 2176);                         // 897 f32
  __hip_bfloat16* whb = (__hip_bfloat16*)(ws + 8192);        // 1M bf16
  __hip_bfloat16* wlb = (__hip_bfloat16*)(ws + 8192 + 2097152);
  __hip_bfloat16* Oh  = (__hip_bfloat16*)(ws + 8192 + 4194304);
  __hip_bfloat16* Ol  = Oh + (size_t)5888 * 1024;

  // Sp (8.9 MB) aliased onto the Oh region: qk_partial writes it, attn_finalize
  // consumes it, then pv_all overwrites Oh/Ol. Stream-ordered, safe.
  float* Sp = (float*)Oh;
  // P (2.9 MB) lives in the tail of d_out: finalize writes, pv reads, gemm
  // overwrites all of d_out afterwards. Stream-ordered, safe.
  float* P  = out + (24117248 - 753664);

  prep_kernel<<<8198, 256, 0, stream>>>(htab, habs, ltab, labs, hw, lw, pe_h, pe_l, whb, wlb);
  qk_partial<<<2048, 256, 0, stream>>>(xh0, xh1, xh2, xl0, xl1, xl2, Sp);
  attn_finalize<<<1024, 256, 0, stream>>>(Sp, pe_h, pe_l, P);
  pv_all<<<2048, 256, 0, stream>>>(xh0, xh1, xh2, xl0, xl1, xl2, P, Oh, Ol);
  gemm_kernel<<<dim3(46, 8), 256, 0, stream>>>(Oh, whb, hb, out, 5888, 1472, 0);
  gemm_kernel<<<dim3(138, 8), 256, 0, stream>>>(Ol, wlb, lb, out, 17664, 4416, 1472);
}

// Round 4
// 158.991 us; speedup vs baseline: 3.7046x; 1.2382x over previous
//
#include <hip/hip_runtime.h>
#include <hip/hip_bf16.h>
#include <stdint.h>

#define DEV __device__ __forceinline__

typedef float f32x4 __attribute__((ext_vector_type(4)));
typedef __bf16 bf16x8 __attribute__((ext_vector_type(8)));

DEV __bf16 tobf(float x){
  union { __hip_bfloat16 s; __bf16 b; } u; u.s = __float2bfloat16(x); return u.b;
}
DEV float dot4(const float4& a, const float4& b){
  return a.x*b.x + a.y*b.y + a.z*b.z + a.w*b.w;
}
DEV bf16x8 pack8(const float4& a, const float4& b){
  bf16x8 r;
  r[0]=tobf(a.x); r[1]=tobf(a.y); r[2]=tobf(a.z); r[3]=tobf(a.w);
  r[4]=tobf(b.x); r[5]=tobf(b.y); r[6]=tobf(b.z); r[7]=tobf(b.w);
  return r;
}
DEV uint32_t f2bf2(float x, float y){
  union { __hip_bfloat16 b[2]; uint32_t u; } cv;
  cv.b[0] = __float2bfloat16(x); cv.b[1] = __float2bfloat16(y);
  return cv.u;
}

// relative-coordinate values (matches reference _rel_index, f32 semantics)
DEV float relc(int j){
  if (j < 17) return (float)(j - 8);
  if (j < 22) return (float)(j - 19) * 3.4f;   // (i-2) * 17/5
  return 0.0f;
}
DEV int band_of(int t){ return t < 17 ? 0 : (t < 22 ? 1 : 2); }

// avgpool1d index map over the concatenated 23-axis -> 13 pooled slots.
template<int MODE> DEV void pool_map(int u, int& a, int& b){
  if (MODE == 0){ a = u; b = u; return; }
  if (u == 0){ a = 0; b = 0; }
  else if (u < 9){ a = 2*u - 1; b = 2*u; }
  else if (u == 9){ a = 17; b = 17; }
  else if (u < 12){ a = 2*u - 2; b = 2*u - 1; }
  else { a = 22; b = 22; }
}

DEV float interp_tab(const float* tab, int H, int h, int t, int u){
  float idx = relc(t) - relc(u) + 16.0f;
  float fl = floorf(idx);
  float ce = ceilf(idx);
  int fi = (int)fminf(fmaxf(fl, 0.f), 1088.f);
  int ci = (int)fminf(fmaxf(ce, 0.f), 1088.f);
  float w = idx - fl;
  return (1.0f - w) * tab[fi*H + h] + w * tab[ci*H + h];
}

// ---------------- prep: pos-embed tables + weight bf16 conversion ----------------
__global__ __launch_bounds__(256) void prep_kernel(
    const float* __restrict__ htab, const float* __restrict__ habs,
    const float* __restrict__ ltab, const float* __restrict__ labs,
    const float* __restrict__ hw, const float* __restrict__ lw,
    float* __restrict__ pe_h, float* __restrict__ pe_l,
    __hip_bfloat16* __restrict__ whb, __hip_bfloat16* __restrict__ wlb)
{
  int i = blockIdx.x * 256 + threadIdx.x;
  if (i < 1048576){ whb[i] = __float2bfloat16(hw[i]); return; }
  if (i < 2097152){ int k = i - 1048576; wlb[k] = __float2bfloat16(lw[k]); return; }
  int j = i - 2097152;
  if (j < 529){
    int t = j / 23, u = j % 23;
    pe_h[j] = interp_tab(htab, 1, 0, t, u) + habs[band_of(t)];
    return;
  }
  j -= 529;
  if (j < 897){
    int h = j / 299, r = j % 299, t = r / 13, u = r % 13;
    int a, b; pool_map<1>(u, a, b);
    float v = 0.5f * (interp_tab(ltab, 3, h, t, a) + interp_tab(ltab, 3, h, t, b));
    pe_l[j] = v + labs[band_of(t)*3 + h];  // pe_l[(h*23+t)*13+u]
  }
}

// ---------------- QK^T partial: one block per (group, s-half) ----------------
template<int MODE>
DEV void qk_group(int gm, int hh,
    const float* __restrict__ x0, const float* __restrict__ x1, const float* __restrict__ x2,
    float* __restrict__ SpB,
    float* Spart /*[4][32][33]*/, float* qnp /*[4][32]*/, float* knp /*[4][32]*/)
{
  constexpr int U = (MODE == 0) ? 23 : 13;
  constexpr int H = (MODE == 0) ? 1 : 3;
  int b, h, d;
  if (MODE == 0){ b = gm >> 6; h = 0; d = gm & 63; }
  else { b = gm / 192; int r = gm % 192; h = r >> 6; d = r & 63; }

  const int tid  = threadIdx.x;
  const int lane = tid & 63;
  const int w    = tid >> 6;
  const int lrow = lane & 15;
  const int kq   = lane >> 4;

  auto base_of = [&](int sel, int band) -> const float* {
    if (band == 0) return x0 + (size_t)((((sel*4 + b)*H + h)*64 + d)*17) * 1024;
    if (band == 1) return x1 + (size_t)((((sel*4 + b)*H + h)*64 + d)*5) * 1024;
    return x2 + (size_t)(((sel*4 + b)*H + h)*64 + d) * 1024;
  };
  const float* qb0 = base_of(0,0); const float* qb1 = base_of(0,1); const float* qb2 = base_of(0,2);
  const float* kb0 = base_of(1,0); const float* kb1 = base_of(1,1); const float* kb2 = base_of(1,2);

  auto rowp = [&](const float* r0, const float* r1, const float* r2, int t) -> const float* {
    if (t < 17) return r0 + (size_t)t * 1024;
    if (t < 22) return r1 + (size_t)(t - 17) * 1024;
    return r2;
  };

  const float* qr[2]; bool qv[2];
  #pragma unroll
  for (int mi = 0; mi < 2; ++mi){
    int t = mi*16 + lrow;
    qv[mi] = (t < 23);
    qr[mi] = qv[mi] ? rowp(qb0,qb1,qb2,t) : qb0;
  }
  const float* krA[2]; const float* krB[2]; bool kv[2];
  #pragma unroll
  for (int ni = 0; ni < 2; ++ni){
    int u = ni*16 + lrow;
    kv[ni] = (u < U);
    int au, bu; pool_map<MODE>(kv[ni] ? u : 0, au, bu);
    krA[ni] = rowp(kb0,kb1,kb2,au);
    krB[ni] = rowp(kb0,kb1,kb2,bu);
  }

  f32x4 acc[2][2] = {};
  float qss[2] = {0.f, 0.f}, kss[2] = {0.f, 0.f};
  const int sbase = hh*512 + w*128 + kq*8;

  #pragma unroll 2
  for (int kk = 0; kk < 4; ++kk){
    const int s = sbase + kk*32;
    bf16x8 qf[2], kf[2];
    #pragma unroll
    for (int mi = 0; mi < 2; ++mi){
      float4 v0 = {0,0,0,0}, v1 = {0,0,0,0};
      if (qv[mi]){
        v0 = *(const float4*)(qr[mi] + s);
        v1 = *(const float4*)(qr[mi] + s + 4);
      }
      qss[mi] += dot4(v0,v0) + dot4(v1,v1);
      qf[mi] = pack8(v0, v1);
    }
    #pragma unroll
    for (int ni = 0; ni < 2; ++ni){
      float4 v0 = {0,0,0,0}, v1 = {0,0,0,0};
      if ((MODE == 0 || ni == 0) && kv[ni]){
        if (MODE == 0){
          v0 = *(const float4*)(krA[ni] + s);
          v1 = *(const float4*)(krA[ni] + s + 4);
        } else {
          float4 a0 = *(const float4*)(krA[ni] + s);
          float4 a1 = *(const float4*)(krA[ni] + s + 4);
          float4 b0 = *(const float4*)(krB[ni] + s);
          float4 b1 = *(const float4*)(krB[ni] + s + 4);
          v0.x = 0.5f*(a0.x+b0.x); v0.y = 0.5f*(a0.y+b0.y); v0.z = 0.5f*(a0.z+b0.z); v0.w = 0.5f*(a0.w+b0.w);
          v1.x = 0.5f*(a1.x+b1.x); v1.y = 0.5f*(a1.y+b1.y); v1.z = 0.5f*(a1.z+b1.z); v1.w = 0.5f*(a1.w+b1.w);
        }
      }
      kss[ni] += dot4(v0,v0) + dot4(v1,v1);
      kf[ni] = pack8(v0, v1);
    }
    #pragma unroll
    for (int mi = 0; mi < 2; ++mi){
      #pragma unroll
      for (int ni = 0; ni < 2; ++ni){
        if (MODE == 0 || ni == 0)
          acc[mi][ni] = __builtin_amdgcn_mfma_f32_16x16x32_bf16(qf[mi], kf[ni], acc[mi][ni], 0, 0, 0);
      }
    }
  }

  #pragma unroll
  for (int i = 0; i < 2; ++i){
    qss[i] += __shfl_xor(qss[i], 16); qss[i] += __shfl_xor(qss[i], 32);
    kss[i] += __shfl_xor(kss[i], 16); kss[i] += __shfl_xor(kss[i], 32);
  }
  if (lane < 16){
    qnp[w*32 + lane]      = qss[0];
    qnp[w*32 + 16 + lane] = qss[1];
    knp[w*32 + lane]      = kss[0];
    knp[w*32 + 16 + lane] = kss[1];
  }
  #pragma unroll
  for (int mi = 0; mi < 2; ++mi)
    #pragma unroll
    for (int ni = 0; ni < 2; ++ni)
      #pragma unroll
      for (int j = 0; j < 4; ++j)
        Spart[w*1056 + (mi*16 + kq*4 + j)*33 + ni*16 + lrow] = acc[mi][ni][j];
  __syncthreads();

  // emit per-block partials: S[32][32] + qn[32] + kn[32]  (1088 floats)
  if (tid < 32){
    SpB[1024 + tid] = qnp[tid] + qnp[32+tid] + qnp[64+tid] + qnp[96+tid];
  } else if (tid < 64){
    int c = tid - 32;
    SpB[1056 + c] = knp[c] + knp[32+c] + knp[64+c] + knp[96+c];
  }
  {
    int r  = tid >> 3;
    int c0 = (tid & 7) * 4;
    float4 o;
    o.x = Spart[r*33+c0+0] + Spart[1056+r*33+c0+0] + Spart[2112+r*33+c0+0] + Spart[3168+r*33+c0+0];
    o.y = Spart[r*33+c0+1] + Spart[1056+r*33+c0+1] + Spart[2112+r*33+c0+1] + Spart[3168+r*33+c0+1];
    o.z = Spart[r*33+c0+2] + Spart[1056+r*33+c0+2] + Spart[2112+r*33+c0+2] + Spart[3168+r*33+c0+2];
    o.w = Spart[r*33+c0+3] + Spart[1056+r*33+c0+3] + Spart[2112+r*33+c0+3] + Spart[3168+r*33+c0+3];
    *(float4*)(SpB + r*32 + c0) = o;
  }
}

__global__ __launch_bounds__(256) void qk_partial(
    const float* __restrict__ xh0, const float* __restrict__ xh1, const float* __restrict__ xh2,
    const float* __restrict__ xl0, const float* __restrict__ xl1, const float* __restrict__ xl2,
    float* __restrict__ Sp)
{
  __shared__ __align__(16) float Spart[4*32*33];
  __shared__ float qnp[4*32], knp[4*32];
  int bid = blockIdx.x;
  int g = bid >> 1, hh = bid & 1;
  float* SpB = Sp + (size_t)bid * 1088;
  if (g < 256) qk_group<0>(g, hh, xh0, xh1, xh2, SpB, Spart, qnp, knp);
  else         qk_group<1>(g - 256, hh, xl0, xl1, xl2, SpB, Spart, qnp, knp);
}

// ---------------- finalize: combine halves, l2norm scale, +pe, softmax -> P ----------------
__global__ __launch_bounds__(256) void attn_finalize(
    const float* __restrict__ Sp, const float* __restrict__ pe_h, const float* __restrict__ pe_l,
    float* __restrict__ P)
{
  int g = blockIdx.x;
  int tid = threadIdx.x;
  int r = tid >> 3, c0 = (tid & 7) * 4;
  const float* A = Sp + (size_t)(2*g) * 1088;
  const float* B = A + 1088;
  float qn = A[1024 + r] + B[1024 + r];
  float iqn = 1.0f / fmaxf(sqrtf(qn), 1e-12f);
  int U, h;
  if (g < 256){ U = 23; h = 0; }
  else { U = 13; h = ((g - 256) % 192) >> 6; }
  float vals[4];
  #pragma unroll
  for (int j = 0; j < 4; ++j){
    int c = c0 + j;
    float sv = A[r*32 + c] + B[r*32 + c];
    float kn = A[1056 + c] + B[1056 + c];
    float ikn = 1.0f / fmaxf(sqrtf(kn), 1e-12f);
    bool valid = (r < 23) && (c < U);
    if (valid){
      float pv = (g < 256) ? pe_h[r*23 + c] : pe_l[(h*23 + r)*13 + c];
      vals[j] = sv * iqn * ikn + pv;
    } else vals[j] = -3.0e38f;
  }
  float m = fmaxf(fmaxf(vals[0], vals[1]), fmaxf(vals[2], vals[3]));
  m = fmaxf(m, __shfl_xor(m, 1)); m = fmaxf(m, __shfl_xor(m, 2)); m = fmaxf(m, __shfl_xor(m, 4));
  float e[4], ssum = 0.f;
  #pragma unroll
  for (int j = 0; j < 4; ++j){ e[j] = __expf(vals[j] - m); ssum += e[j]; }
  ssum += __shfl_xor(ssum, 1); ssum += __shfl_xor(ssum, 2); ssum += __shfl_xor(ssum, 4);
  float inv = 1.0f / ssum;
  if (r < 23){
    #pragma unroll
    for (int j = 0; j < 4; ++j){
      int c = c0 + j;
      bool valid = (c < U);
      P[(size_t)g*736 + r*32 + c] = valid ? e[j] * inv : 0.f;
    }
  }
}

// ---------------- PV: streaming, one block per (group, s-half) ----------------
template<int MODE>
DEV void pv_group(int gm, int sh,
    const float* __restrict__ x0, const float* __restrict__ x1, const float* __restrict__ x2,
    const float* __restrict__ Pg, __hip_bfloat16* __restrict__ Og, float* lds_p)
{
  constexpr int U  = (MODE == 0) ? 23 : 13;
  constexpr int UP = (MODE == 0) ? 24 : 16;
  constexpr int H  = (MODE == 0) ? 1 : 3;
  int b, h, d;
  if (MODE == 0){ b = gm >> 6; h = 0; d = gm & 63; }
  else { b = gm / 192; int r = gm % 192; h = r >> 6; d = r & 63; }
  const int tid = threadIdx.x;

  if (tid < 184) *(float4*)(lds_p + tid*4) = *(const float4*)(Pg + tid*4);
  __syncthreads();

  const float* vb0 = x0 + (size_t)((((2*4 + b)*H + h)*64 + d)*17) * 1024;
  const float* vb1 = x1 + (size_t)((((2*4 + b)*H + h)*64 + d)*5) * 1024;
  const float* vb2 = x2 + (size_t)(((2*4 + b)*H + h)*64 + d) * 1024;
  auto rowp = [&](int t) -> const float* {
    if (t < 17) return vb0 + (size_t)t * 1024;
    if (t < 22) return vb1 + (size_t)(t - 17) * 1024;
    return vb2;
  };

  const int s0 = sh*512 + tid*2;
  float2 vv[UP];
  #pragma unroll
  for (int u = 0; u < UP; ++u){
    if (u < U){
      int au, bu; pool_map<MODE>(u, au, bu);
      float2 a = *(const float2*)(rowp(au) + s0);
      if (MODE == 0) vv[u] = a;
      else {
        float2 c = *(const float2*)(rowp(bu) + s0);
        vv[u].x = 0.5f*(a.x + c.x); vv[u].y = 0.5f*(a.y + c.y);
      }
    } else { vv[u].x = 0.f; vv[u].y = 0.f; }
  }

  #pragma unroll 2
  for (int t = 0; t < 23; ++t){
    float ax = 0.f, ay = 0.f;
    #pragma unroll
    for (int u4 = 0; u4 < UP/4; ++u4){
      float4 p = *(const float4*)(lds_p + t*32 + u4*4);
      ax += p.x*vv[u4*4+0].x + p.y*vv[u4*4+1].x + p.z*vv[u4*4+2].x + p.w*vv[u4*4+3].x;
      ay += p.x*vv[u4*4+0].y + p.y*vv[u4*4+1].y + p.z*vv[u4*4+2].y + p.w*vv[u4*4+3].y;
    }
    *(uint32_t*)((__hip_bfloat16*)Og + (size_t)t*1024 + s0) = f2bf2(ax, ay);
  }
}

__global__ __launch_bounds__(256) void pv_all(
    const float* __restrict__ xh0, const float* __restrict__ xh1, const float* __restrict__ xh2,
    const float* __restrict__ xl0, const float* __restrict__ xl1, const float* __restrict__ xl2,
    const float* __restrict__ P,
    __hip_bfloat16* __restrict__ Oh, __hip_bfloat16* __restrict__ Ol)
{
  __shared__ __align__(16) float lds_p[736];
  int bid = blockIdx.x;
  int g = bid >> 1, sh = bid & 1;
  if (g < 256) pv_group<0>(g, sh, xh0, xh1, xh2, P + (size_t)g*736, Oh + (size_t)g*23552, lds_p);
  else {
    int gm = g - 256;
    pv_group<1>(gm, sh, xl0, xl1, xl2, P + (size_t)g*736, Ol + (size_t)gm*23552, lds_p);
  }
}

// ---------------- merged projection GEMM ----------------
// A = [Oh|Ol] 23552x1024 bf16. 128x128 tile, BK=64, double-buffered LDS with
// prefetch-before-compute (T3 minimal 2-phase), XOR-swizzled LDS via
// pre-swizzled global source (rule #21), XCD-chunked block swizzle (T1).
__global__ __launch_bounds__(256) void gemm_merged(
    const __hip_bfloat16* __restrict__ A,
    const __hip_bfloat16* __restrict__ Wh, const __hip_bfloat16* __restrict__ Wl,
    const float* __restrict__ bh, const float* __restrict__ bl,
    float* __restrict__ out)
{
  __shared__ __hip_bfloat16 lA[2][128*64];
  __shared__ __hip_bfloat16 lB[2][128*64];
  const int tid  = threadIdx.x;
  const int lane = tid & 63;

  // 1472 blocks = 8 XCDs x 184; XCD x owns 23 consecutive M-panels, 8 N-tiles each
  const int bid = blockIdx.x;
  const int swz = (bid & 7) * 184 + (bid >> 3);
  const int mt = swz >> 3, nt = swz & 7;
  const int tM = mt * 128, tN = nt * 128;
  const bool hifi = (mt < 46);
  const __hip_bfloat16* W = hifi ? Wh : Wl;
  const float* bias = hifi ? bh : bl;

  const int wm = ((tid >> 6) >> 1) * 64, wn = ((tid >> 6) & 1) * 64;
  f32x4 acc[4][4] = {};

  const int srow = tid >> 3;                               // 0..31
  const int scol = ((tid & 7) * 8) ^ ((srow & 7) * 8);     // pre-swizzled source col (elems)
  const __hip_bfloat16* ga = A + (size_t)(tM + srow) * 1024 + scol;
  const __hip_bfloat16* gb = W + (size_t)(tN + srow) * 1024 + scol;

  auto stage = [&](int buf, int k0){
    #pragma unroll
    for (int q = 0; q < 4; ++q){
      __builtin_amdgcn_global_load_lds(
        (const __attribute__((address_space(1))) void*)(ga + k0 + (size_t)q*32*1024),
        (__attribute__((address_space(3))) void*)(&lA[buf][q*2048 + tid*8]), 16, 0, 0);
      __builtin_amdgcn_global_load_lds(
        (const __attribute__((address_space(1))) void*)(gb + k0 + (size_t)q*32*1024),
        (__attribute__((address_space(3))) void*)(&lB[buf][q*2048 + tid*8]), 16, 0, 0);
    }
  };

  const int rsw = (lane & 7) * 8;   // read-side swizzle (elems): same involution
  auto compute = [&](int buf){
    #pragma unroll
    for (int kk = 0; kk < 2; ++kk){
      const int cb = (kk*32 + (lane >> 4)*8) ^ rsw;
      bf16x8 af[4], bfr[4];
      #pragma unroll
      for (int mi = 0; mi < 4; ++mi)
        af[mi] = *(const bf16x8*)(&lA[buf][(wm + mi*16 + (lane & 15))*64 + cb]);
      #pragma unroll
      for (int ni = 0; ni < 4; ++ni)
        bfr[ni] = *(const bf16x8*)(&lB[buf][(wn + ni*16 + (lane & 15))*64 + cb]);
      #pragma unroll
      for (int mi = 0; mi < 4; ++mi){
        #pragma unroll
        for (int ni = 0; ni < 4; ++ni)
          acc[mi][ni] = __builtin_amdgcn_mfma_f32_16x16x32_bf16(af[mi], bfr[ni], acc[mi][ni], 0, 0, 0);
      }
    }
  };

  stage(0, 0);
  __syncthreads();
  int cur = 0;
  #pragma unroll 1
  for (int t = 0; t < 15; ++t){
    stage(cur ^ 1, (t + 1) * 64);   // issue next-tile loads FIRST (overlap with compute)
    compute(cur);
    __syncthreads();                // drains vmcnt+lgkmcnt, then barrier
    cur ^= 1;
  }
  compute(cur);

  // epilogue: bias + scattered row remap into concat'd channel layout
  float bs[4];
  #pragma unroll
  for (int ni = 0; ni < 4; ++ni) bs[ni] = bias[tN + wn + ni*16 + (lane & 15)];
  #pragma unroll
  for (int mi = 0; mi < 4; ++mi){
    #pragma unroll
    for (int j = 0; j < 4; ++j){
      int r = tM + wm + mi*16 + (lane >> 4)*4 + j;
      size_t orow;
      if (r < 5888){ orow = (size_t)(r / 1472) * 5888 + (r % 1472); }
      else { int rr = r - 5888; orow = (size_t)(rr / 4416) * 5888 + 1472 + (rr % 4416); }
      float* po = out + orow * 1024 + tN + wn + (lane & 15);
      #pragma unroll
      for (int ni = 0; ni < 4; ++ni)
        po[ni*16] = acc[mi][ni][j] + bs[ni];
    }
  }
}

extern "C" void kernel_launch(void* const* d_in, const int* in_sizes, int n_in,
                              void* d_out, int out_size, void* d_ws, size_t ws_size,
                              hipStream_t stream) {
  const float* xh0  = (const float*)d_in[0];
  const float* xh1  = (const float*)d_in[1];
  const float* xh2  = (const float*)d_in[2];
  const float* xl0  = (const float*)d_in[3];
  const float* xl1  = (const float*)d_in[4];
  const float* xl2  = (const float*)d_in[5];
  const float* htab = (const float*)d_in[6];
  const float* habs = (const float*)d_in[7];
  const float* ltab = (const float*)d_in[8];
  const float* labs = (const float*)d_in[9];
  const float* hw   = (const float*)d_in[10];
  const float* hb   = (const float*)d_in[11];
  const float* lw   = (const float*)d_in[12];
  const float* lb   = (const float*)d_in[13];
  float* out = (float*)d_out;

  char* ws = (char*)d_ws;
  float* pe_h = (float*)ws;                                  // 529 f32
  float* pe_l = (float*)(ws + 2176);                         // 897 f32
  __hip_bfloat16* whb = (__hip_bfloat16*)(ws + 8192);        // 1M bf16
  __hip_bfloat16* wlb = (__hip_bfloat16*)(ws + 8192 + 2097152);
  __hip_bfloat16* Oh  = (__hip_bfloat16*)(ws + 8192 + 4194304);
  __hip_bfloat16* Ol  = Oh + (size_t)5888 * 1024;

  // Sp (8.9 MB) aliased onto the Oh region: qk_partial writes it, attn_finalize
  // consumes it, then pv_all overwrites Oh/Ol. Stream-ordered, safe.
  float* Sp = (float*)Oh;
  // P (2.9 MB) lives in the tail of d_out: finalize writes, pv reads, gemm
  // overwrites all of d_out afterwards. Stream-ordered, safe.
  float* P  = out + (24117248 - 753664);

  prep_kernel<<<8198, 256, 0, stream>>>(htab, habs, ltab, labs, hw, lw, pe_h, pe_l, whb, wlb);
  qk_partial<<<2048, 256, 0, stream>>>(xh0, xh1, xh2, xl0, xl1, xl2, Sp);
  attn_finalize<<<1024, 256, 0, stream>>>(Sp, pe_h, pe_l, P);
  pv_all<<<2048, 256, 0, stream>>>(xh0, xh1, xh2, xl0, xl1, xl2, P, Oh, Ol);
  gemm_merged<<<1472, 256, 0, stream>>>(Oh, whb, wlb, hb, lb, out);
}